// Round 11
// baseline (17276.007 us; speedup 1.0000x reference)
//
#include <hip/hip_runtime.h>
#include <math.h>

#define T_LEN 1000
#define BATCH 16
#define MEL   80
#define HID   512
#define NCLS  64
#define SL    8        // blocks per chain (8 x 512 threads = 64 waves/chain)

__device__ __forceinline__ float fast_tanh(float x) {
    float e = __expf(2.0f * x);
    return 1.0f - 2.0f / (e + 1.0f);
}
__device__ __forceinline__ float fast_sigmoid(float x) {
    return 1.0f / (1.0f + __expf(-x));
}

// pack/unpack (value, epoch) in one 8B atom. Stored/loaded ONLY via
// __hip_atomic_{store,load} AGENT — the proven-safe primitive class
// (r7/r8 lesson: asm sc-flag loads in spin loops livelock).
__device__ __forceinline__ unsigned long long pack_pair(float v, unsigned e) {
    return ((unsigned long long)e << 32) | (unsigned long long)__float_as_uint(v);
}
__device__ __forceinline__ float pair_val(unsigned long long p) {
    return __uint_as_float((unsigned)(p & 0xffffffffull));
}
__device__ __forceinline__ unsigned pair_epoch(unsigned long long p) {
    return (unsigned)(p >> 32);
}

// one-shot LLC weight load: 2 contiguous float4 (asm-defined => cannot be
// rematerialized => register-resident). NOT used in spin loops.
__device__ __forceinline__ void llc_load2(const float* base, float4& a, float4& b) {
    asm volatile(
        "global_load_dwordx4 %0, %2, off sc0 sc1\n\t"
        "global_load_dwordx4 %1, %2, off offset:16 sc0 sc1\n\t"
        "s_waitcnt vmcnt(0)"
        : "=&v"(a), "=&v"(b)
        : "v"(base)
        : "memory");
}

// K0: init pair buffers to epoch 0 (never matches poll targets >= 1)
__global__ void k0_init(unsigned long long* hp, unsigned long long* ep) {
    int i = blockIdx.x * 256 + threadIdx.x;
    if (i < BATCH * HID) { hp[i] = 0ull; ep[i] = 0ull; }
}

// K1: per t: x_norm0 from feats, be0 = x_norm0 @ B0^T
__global__ __launch_bounds__(256) void k1_be0(const float* __restrict__ feats,
                                              const float* __restrict__ B0,
                                              float* __restrict__ be0) {
    const int t = blockIdx.x;
    const int tid = threadIdx.x;
    __shared__ float xf[BATCH][MEL];
    __shared__ float sc[BATCH];
    for (int idx = tid; idx < BATCH * MEL; idx += 256) {
        int b = idx / MEL, m = idx % MEL;
        xf[b][m] = feats[b * (T_LEN * MEL) + t * MEL + m];
    }
    __syncthreads();
    if (tid < BATCH) {
        float ss = 0.f;
        for (int m = 0; m < MEL; ++m) { float v = xf[tid][m]; ss += v * v; }
        sc[tid] = fmaxf(sqrtf(ss), 1e-6f);
    }
    __syncthreads();
    for (int idx = tid; idx < BATCH * MEL; idx += 256) {
        int b = idx / MEL, m = idx % MEL;
        float v = xf[b][m] / sc[b];
        xf[b][m] = fminf(fmaxf(v, -1.f), 1.f);
    }
    __syncthreads();
    for (int j = tid; j < HID; j += 256) {
        float acc[BATCH];
        #pragma unroll
        for (int b = 0; b < BATCH; ++b) acc[b] = 0.f;
        const float* brow = B0 + j * MEL;
        for (int k = 0; k < MEL; k += 4) {
            float4 w = *(const float4*)(brow + k);
            #pragma unroll
            for (int b = 0; b < BATCH; ++b) {
                float4 xv = *(const float4*)(&xf[b][k]);
                acc[b] += w.x * xv.x + w.y * xv.y + w.z * xv.z + w.w * xv.w;
            }
        }
        #pragma unroll
        for (int b = 0; b < BATCH; ++b)
            be0[(t * BATCH + b) * HID + j] = acc[b];
    }
}

// K2: per t: x_norm1 from be0, be1 = x_norm1 @ B1^T, store xs1
__global__ __launch_bounds__(256) void k2_be1(const float* __restrict__ be0,
                                              const float* __restrict__ B1,
                                              float* __restrict__ be1,
                                              float* __restrict__ xs1) {
    const int t = blockIdx.x;
    const int tid = threadIdx.x;
    __shared__ float xn[BATCH][HID];
    __shared__ float sc[BATCH];
    __shared__ float psum[BATCH][16];
    for (int idx = tid; idx < BATCH * HID; idx += 256) {
        int b = idx >> 9, k = idx & 511;
        xn[b][k] = be0[(t * BATCH + b) * HID + k];
    }
    __syncthreads();
    {
        int b = tid >> 4, l = tid & 15;
        float ss = 0.f;
        for (int k = l; k < HID; k += 16) { float v = xn[b][k]; ss += v * v; }
        psum[b][l] = ss;
    }
    __syncthreads();
    if (tid < BATCH) {
        float ss = 0.f;
        #pragma unroll
        for (int l = 0; l < 16; ++l) ss += psum[tid][l];
        float s = fmaxf(sqrtf(ss), 1e-6f);
        sc[tid] = s;
        xs1[t * BATCH + tid] = s;
    }
    __syncthreads();
    for (int idx = tid; idx < BATCH * HID; idx += 256) {
        int b = idx >> 9, k = idx & 511;
        float v = xn[b][k] / sc[b];
        xn[b][k] = fminf(fmaxf(v, -1.f), 1.f);
    }
    __syncthreads();
    for (int j = tid; j < HID; j += 256) {
        float acc[BATCH];
        #pragma unroll
        for (int b = 0; b < BATCH; ++b) acc[b] = 0.f;
        const float* brow = B1 + j * HID;
        for (int k = 0; k < HID; k += 4) {
            float4 w = *(const float4*)(brow + k);
            #pragma unroll
            for (int b = 0; b < BATCH; ++b) {
                float4 xv = *(const float4*)(&xn[b][k]);
                acc[b] += w.x * xv.x + w.y * xv.y + w.z * xv.z + w.w * xv.w;
            }
        }
        #pragma unroll
        for (int b = 0; b < BATCH; ++b)
            be1[(t * BATCH + b) * HID + j] = acc[b];
    }
}

// K3: sequential recurrence, fully wave-autonomous. 64 waves/chain; wave owns
// 8 columns, lane L owns k-slice [8L,8L+8). Exchange via packed (value,epoch)
// u64 atoms: self-validating polls (data IS the flag). Zero duplication: each
// wave loads each vector element exactly once per phase. No LDS, no barriers,
// no drains. Cross-lane sums via 6-level shfl_xor butterfly.
__global__ __launch_bounds__(512, 1) void k3_lane(
    const float* __restrict__ be0, const float* __restrict__ be1,
    const float* __restrict__ xs1,
    const float* __restrict__ C1, const float* __restrict__ W1,
    const float* __restrict__ a1, const float* __restrict__ tau,
    const float* __restrict__ gam,
    float* __restrict__ h1s,
    unsigned long long* hp, unsigned long long* ep)
{
    const int chain = blockIdx.x & 15;
    const int slice = blockIdx.x >> 4;        // 0..7
    const int tid = threadIdx.x;
    const int w = tid >> 6;                   // wave in block 0..7
    const int lane = tid & 63;
    const int wave_id = slice * 8 + w;        // 0..63
    const int col_base = wave_id * 8;         // wave's 8 columns
    const int mycol = col_base + (lane & 7);  // column for lanes 0..7
    const bool owner = (lane < 8);

    // weights: 8 cols x 8 k-values per matrix = 2x64 floats = 128 VGPRs,
    // asm-defined => register-resident.
    float4 wCa[8], wCb[8], wWa[8], wWb[8];
    #pragma unroll
    for (int jj = 0; jj < 8; ++jj) {
        const size_t row = (size_t)(col_base + jj) * HID + 8 * lane;
        llc_load2(C1 + row, wCa[jj], wCb[jj]);
        llc_load2(W1 + row, wWa[jj], wWb[jj]);
    }
    const float tauv = tau[0], gamv = gam[0];
    const float siga = fast_sigmoid(a1[mycol]);

    unsigned long long* hp_c = hp + (size_t)chain * HID;
    unsigned long long* ep_c = ep + (size_t)chain * HID;
    const int kbase = 8 * lane;               // lane's k-slice

    float hj = 0.f;
    float cur_be0 = 0.f, cur_be1 = 0.f;
    if (owner) {
        cur_be0 = __builtin_nontemporal_load(&be0[(size_t)chain * HID + mycol]);
        cur_be1 = __builtin_nontemporal_load(&be1[(size_t)chain * HID + mycol]);
    }
    float cur_xs = __builtin_nontemporal_load(&xs1[chain]);

    for (int t = 0; t < T_LEN; ++t) {
        // prefetch next step's streams (overlaps polls)
        float nxt_be0 = 0.f, nxt_be1 = 0.f, nxt_xs = 0.f;
        if (t + 1 < T_LEN) {
            const size_t nrow = (size_t)((t + 1) * BATCH + chain) * HID;
            if (owner) {
                nxt_be0 = __builtin_nontemporal_load(&be0[nrow + mycol]);
                nxt_be1 = __builtin_nontemporal_load(&be1[nrow + mycol]);
            }
            nxt_xs = __builtin_nontemporal_load(&xs1[(t + 1) * BATCH + chain]);
        }
        const unsigned tag = (unsigned)(t + 1);

        // ---- phase 1: poll h(t) (epoch t; t=0 known zero), dp = h @ C1^T ----
        float hv[8];
        if (t == 0) {
            #pragma unroll
            for (int m = 0; m < 8; ++m) hv[m] = 0.f;
        } else {
            const unsigned want = (unsigned)t;
            unsigned long long pv[8];
            for (;;) {
                bool ok = true;
                #pragma unroll
                for (int m = 0; m < 8; ++m) {
                    pv[m] = __hip_atomic_load(&hp_c[kbase + m], __ATOMIC_RELAXED,
                                              __HIP_MEMORY_SCOPE_AGENT);
                    ok = ok && (pair_epoch(pv[m]) == want);
                }
                if (__all(ok)) break;
                __builtin_amdgcn_s_sleep(1);
            }
            #pragma unroll
            for (int m = 0; m < 8; ++m) hv[m] = pair_val(pv[m]);
        }
        float dp[8];
        #pragma unroll
        for (int jj = 0; jj < 8; ++jj) {
            dp[jj] = wCa[jj].x * hv[0] + wCa[jj].y * hv[1]
                   + wCa[jj].z * hv[2] + wCa[jj].w * hv[3]
                   + wCb[jj].x * hv[4] + wCb[jj].y * hv[5]
                   + wCb[jj].z * hv[6] + wCb[jj].w * hv[7];
        }
        #pragma unroll
        for (int mask = 1; mask < 64; mask <<= 1) {
            #pragma unroll
            for (int jj = 0; jj < 8; ++jj)
                dp[jj] += __shfl_xor(dp[jj], mask, 64);
        }
        if (owner) {
            float e = cur_be0 - fast_tanh(dp[lane & 7]) * cur_xs;
            __hip_atomic_store(&ep_c[mycol], pack_pair(e, tag),
                               __ATOMIC_RELAXED, __HIP_MEMORY_SCOPE_AGENT);
        }

        // ---- phase 2: poll err(t) (epoch t+1), ee = err @ W1^T, exact ssq ----
        float evv[8];
        {
            unsigned long long pv[8];
            for (;;) {
                bool ok = true;
                #pragma unroll
                for (int m = 0; m < 8; ++m) {
                    pv[m] = __hip_atomic_load(&ep_c[kbase + m], __ATOMIC_RELAXED,
                                              __HIP_MEMORY_SCOPE_AGENT);
                    ok = ok && (pair_epoch(pv[m]) == tag);
                }
                if (__all(ok)) break;
                __builtin_amdgcn_s_sleep(1);
            }
            #pragma unroll
            for (int m = 0; m < 8; ++m) evv[m] = pair_val(pv[m]);
        }
        float ee[8];
        float sq = 0.f;
        #pragma unroll
        for (int m = 0; m < 8; ++m) sq += evv[m] * evv[m];
        #pragma unroll
        for (int jj = 0; jj < 8; ++jj) {
            ee[jj] = wWa[jj].x * evv[0] + wWa[jj].y * evv[1]
                   + wWa[jj].z * evv[2] + wWa[jj].w * evv[3]
                   + wWb[jj].x * evv[4] + wWb[jj].y * evv[5]
                   + wWb[jj].z * evv[6] + wWb[jj].w * evv[7];
        }
        #pragma unroll
        for (int mask = 1; mask < 64; mask <<= 1) {
            sq += __shfl_xor(sq, mask, 64);
            #pragma unroll
            for (int jj = 0; jj < 8; ++jj)
                ee[jj] += __shfl_xor(ee[jj], mask, 64);
        }
        if (owner) {
            float rel = fminf(sqrtf(sq) / cur_xs, 4.0f);
            float s = fast_sigmoid((rel - tauv) / gamv);
            float input_h = hj * 0.2f + cur_be1 * 0.6f + ee[lane & 7] * s * 0.2f;
            float g = s * siga;
            hj = hj * (1.f - g) + fast_tanh(input_h) * g;
            __hip_atomic_store(&hp_c[mycol], pack_pair(hj, tag),
                               __ATOMIC_RELAXED, __HIP_MEMORY_SCOPE_AGENT);
            __builtin_nontemporal_store(hj,
                &h1s[(size_t)(t * BATCH + chain) * HID + mycol]);
        }

        cur_be0 = nxt_be0; cur_be1 = nxt_be1; cur_xs = nxt_xs;
    }
}

// K4: head matmul out[b,t,c] = [h1 || be1] @ head_w^T + head_b
__global__ __launch_bounds__(1024) void k4_head(const float* __restrict__ h1s,
                                                const float* __restrict__ be1,
                                                const float* __restrict__ head_w,
                                                const float* __restrict__ head_b,
                                                float* __restrict__ out) {
    const int t = blockIdx.x;
    const int tid = threadIdx.x;
    const int c = tid >> 4;
    const int b = tid & 15;
    const float* hw = head_w + c * (2 * HID);
    const float* x1 = h1s + (size_t)(t * BATCH + b) * HID;
    const float* x2 = be1 + (size_t)(t * BATCH + b) * HID;
    float acc0 = head_b[c], acc1 = 0.f;
    for (int k = 0; k < HID; k += 4) {
        float4 w = *(const float4*)(hw + k);
        float4 xv = *(const float4*)(x1 + k);
        acc0 += w.x * xv.x + w.y * xv.y + w.z * xv.z + w.w * xv.w;
    }
    for (int k = 0; k < HID; k += 4) {
        float4 w = *(const float4*)(hw + HID + k);
        float4 xv = *(const float4*)(x2 + k);
        acc1 += w.x * xv.x + w.y * xv.y + w.z * xv.z + w.w * xv.w;
    }
    out[b * (T_LEN * NCLS) + t * NCLS + c] = acc0 + acc1;
}

extern "C" void kernel_launch(void* const* d_in, const int* in_sizes, int n_in,
                              void* d_out, int out_size, void* d_ws, size_t ws_size,
                              hipStream_t stream) {
    const float* feats  = (const float*)d_in[0];
    const float* B0     = (const float*)d_in[2];
    const float* C1     = (const float*)d_in[7];
    const float* B1     = (const float*)d_in[8];
    const float* W1     = (const float*)d_in[9];
    const float* a1     = (const float*)d_in[10];
    const float* tau1   = (const float*)d_in[11];
    const float* gam1   = (const float*)d_in[12];
    const float* head_w = (const float*)d_in[13];
    const float* head_b = (const float*)d_in[14];
    float* out = (float*)d_out;

    float* be0 = (float*)d_ws;                          // T*B*HID
    float* be1 = be0 + (size_t)T_LEN * BATCH * HID;     // T*B*HID
    float* xs1 = be1 + (size_t)T_LEN * BATCH * HID;     // T*B
    float* h1s = xs1 + (size_t)T_LEN * BATCH;           // T*B*HID
    unsigned long long* hp =
        (unsigned long long*)(h1s + (size_t)T_LEN * BATCH * HID);  // B*HID u64
    unsigned long long* epr = hp + (size_t)BATCH * HID;            // B*HID u64

    hipLaunchKernelGGL(k0_init, dim3(32), dim3(256), 0, stream, hp, epr);
    hipLaunchKernelGGL(k1_be0, dim3(T_LEN), dim3(256), 0, stream, feats, B0, be0);
    hipLaunchKernelGGL(k2_be1, dim3(T_LEN), dim3(256), 0, stream, be0, B1, be1, xs1);
    hipLaunchKernelGGL(k3_lane, dim3(BATCH * SL), dim3(512), 0, stream,
                       be0, be1, xs1, C1, W1, a1, tau1, gam1, h1s, hp, epr);
    hipLaunchKernelGGL(k4_head, dim3(T_LEN), dim3(1024), 0, stream,
                       h1s, be1, head_w, head_b, out);
}

// Round 12
// 5717.620 us; speedup vs baseline: 3.0215x; 3.0215x over previous
//
#include <hip/hip_runtime.h>
#include <math.h>

#define T_LEN 1000
#define BATCH 16
#define MEL   80
#define HID   512
#define NCLS  64
#define SL    8        // blocks per chain (8 x 512 threads)

__device__ __forceinline__ float fast_tanh(float x) {
    float e = __expf(2.0f * x);
    return 1.0f - 2.0f / (e + 1.0f);
}
__device__ __forceinline__ float fast_sigmoid(float x) {
    return 1.0f / (1.0f + __expf(-x));
}

// packed (value, epoch) 8B atom. Stored/loaded ONLY via __hip_atomic_{store,
// load} AGENT — the proven-safe primitive class (r7/r8: asm polls livelock).
__device__ __forceinline__ unsigned long long pack_pair(float v, unsigned e) {
    return ((unsigned long long)e << 32) | (unsigned long long)__float_as_uint(v);
}
__device__ __forceinline__ float pair_val(unsigned long long p) {
    return __uint_as_float((unsigned)(p & 0xffffffffull));
}
__device__ __forceinline__ unsigned pair_epoch(unsigned long long p) {
    return (unsigned)(p >> 32);
}

// one-shot LLC bulk load for weights (asm-defined => cannot be rematerialized
// => register-resident). NOT used in any spin loop. (r6/r9 proven)
__device__ __forceinline__ void llc_load16(const float* base, float4 (&r)[16]) {
    asm volatile(
        "global_load_dwordx4 %0, %16, off sc0 sc1\n\t"
        "global_load_dwordx4 %1, %16, off offset:128 sc0 sc1\n\t"
        "global_load_dwordx4 %2, %16, off offset:256 sc0 sc1\n\t"
        "global_load_dwordx4 %3, %16, off offset:384 sc0 sc1\n\t"
        "global_load_dwordx4 %4, %16, off offset:512 sc0 sc1\n\t"
        "global_load_dwordx4 %5, %16, off offset:640 sc0 sc1\n\t"
        "global_load_dwordx4 %6, %16, off offset:768 sc0 sc1\n\t"
        "global_load_dwordx4 %7, %16, off offset:896 sc0 sc1\n\t"
        "global_load_dwordx4 %8, %16, off offset:1024 sc0 sc1\n\t"
        "global_load_dwordx4 %9, %16, off offset:1152 sc0 sc1\n\t"
        "global_load_dwordx4 %10, %16, off offset:1280 sc0 sc1\n\t"
        "global_load_dwordx4 %11, %16, off offset:1408 sc0 sc1\n\t"
        "global_load_dwordx4 %12, %16, off offset:1536 sc0 sc1\n\t"
        "global_load_dwordx4 %13, %16, off offset:1664 sc0 sc1\n\t"
        "global_load_dwordx4 %14, %16, off offset:1792 sc0 sc1\n\t"
        "global_load_dwordx4 %15, %16, off offset:1920 sc0 sc1\n\t"
        "s_waitcnt vmcnt(0)"
        : "=&v"(r[0]), "=&v"(r[1]), "=&v"(r[2]), "=&v"(r[3]),
          "=&v"(r[4]), "=&v"(r[5]), "=&v"(r[6]), "=&v"(r[7]),
          "=&v"(r[8]), "=&v"(r[9]), "=&v"(r[10]), "=&v"(r[11]),
          "=&v"(r[12]), "=&v"(r[13]), "=&v"(r[14]), "=&v"(r[15])
        : "v"(base)
        : "memory");
}

// K0: init pair buffers to epoch 0 (never matches poll targets >= 1)
__global__ void k0_init(unsigned long long* hp, unsigned long long* ep) {
    int i = blockIdx.x * 256 + threadIdx.x;
    if (i < BATCH * HID) { hp[i] = 0ull; ep[i] = 0ull; }
}

// K1: per t: x_norm0 from feats, be0 = x_norm0 @ B0^T
__global__ __launch_bounds__(256) void k1_be0(const float* __restrict__ feats,
                                              const float* __restrict__ B0,
                                              float* __restrict__ be0) {
    const int t = blockIdx.x;
    const int tid = threadIdx.x;
    __shared__ float xf[BATCH][MEL];
    __shared__ float sc[BATCH];
    for (int idx = tid; idx < BATCH * MEL; idx += 256) {
        int b = idx / MEL, m = idx % MEL;
        xf[b][m] = feats[b * (T_LEN * MEL) + t * MEL + m];
    }
    __syncthreads();
    if (tid < BATCH) {
        float ss = 0.f;
        for (int m = 0; m < MEL; ++m) { float v = xf[tid][m]; ss += v * v; }
        sc[tid] = fmaxf(sqrtf(ss), 1e-6f);
    }
    __syncthreads();
    for (int idx = tid; idx < BATCH * MEL; idx += 256) {
        int b = idx / MEL, m = idx % MEL;
        float v = xf[b][m] / sc[b];
        xf[b][m] = fminf(fmaxf(v, -1.f), 1.f);
    }
    __syncthreads();
    for (int j = tid; j < HID; j += 256) {
        float acc[BATCH];
        #pragma unroll
        for (int b = 0; b < BATCH; ++b) acc[b] = 0.f;
        const float* brow = B0 + j * MEL;
        for (int k = 0; k < MEL; k += 4) {
            float4 w = *(const float4*)(brow + k);
            #pragma unroll
            for (int b = 0; b < BATCH; ++b) {
                float4 xv = *(const float4*)(&xf[b][k]);
                acc[b] += w.x * xv.x + w.y * xv.y + w.z * xv.z + w.w * xv.w;
            }
        }
        #pragma unroll
        for (int b = 0; b < BATCH; ++b)
            be0[(t * BATCH + b) * HID + j] = acc[b];
    }
}

// K2: per t: x_norm1 from be0, be1 = x_norm1 @ B1^T, store xs1
__global__ __launch_bounds__(256) void k2_be1(const float* __restrict__ be0,
                                              const float* __restrict__ B1,
                                              float* __restrict__ be1,
                                              float* __restrict__ xs1) {
    const int t = blockIdx.x;
    const int tid = threadIdx.x;
    __shared__ float xn[BATCH][HID];
    __shared__ float sc[BATCH];
    __shared__ float psum[BATCH][16];
    for (int idx = tid; idx < BATCH * HID; idx += 256) {
        int b = idx >> 9, k = idx & 511;
        xn[b][k] = be0[(t * BATCH + b) * HID + k];
    }
    __syncthreads();
    {
        int b = tid >> 4, l = tid & 15;
        float ss = 0.f;
        for (int k = l; k < HID; k += 16) { float v = xn[b][k]; ss += v * v; }
        psum[b][l] = ss;
    }
    __syncthreads();
    if (tid < BATCH) {
        float ss = 0.f;
        #pragma unroll
        for (int l = 0; l < 16; ++l) ss += psum[tid][l];
        float s = fmaxf(sqrtf(ss), 1e-6f);
        sc[tid] = s;
        xs1[t * BATCH + tid] = s;
    }
    __syncthreads();
    for (int idx = tid; idx < BATCH * HID; idx += 256) {
        int b = idx >> 9, k = idx & 511;
        float v = xn[b][k] / sc[b];
        xn[b][k] = fminf(fmaxf(v, -1.f), 1.f);
    }
    __syncthreads();
    for (int j = tid; j < HID; j += 256) {
        float acc[BATCH];
        #pragma unroll
        for (int b = 0; b < BATCH; ++b) acc[b] = 0.f;
        const float* brow = B1 + j * HID;
        for (int k = 0; k < HID; k += 4) {
            float4 w = *(const float4*)(brow + k);
            #pragma unroll
            for (int b = 0; b < BATCH; ++b) {
                float4 xv = *(const float4*)(&xn[b][k]);
                acc[b] += w.x * xv.x + w.y * xv.y + w.z * xv.z + w.w * xv.w;
            }
        }
        #pragma unroll
        for (int b = 0; b < BATCH; ++b)
            be1[(t * BATCH + b) * HID + j] = acc[b];
    }
}

// K3: sequential recurrence. 8 blocks/chain x 8 waves; r9's proven compute
// layout (thread = (col, k-chunk), weights register-resident, broadcast LDS
// reads). Exchange via packed (value,epoch) u64 atoms: wave w polls the
// contiguous slice [64w,64w+64) — one coalesced u64 load per lane — stages
// into LDS, one barrier per phase. No drains, no counters, no atomics.
__global__ __launch_bounds__(512, 1) void k3_fused(
    const float* __restrict__ be0, const float* __restrict__ be1,
    const float* __restrict__ xs1,
    const float* __restrict__ C1, const float* __restrict__ W1,
    const float* __restrict__ a1, const float* __restrict__ tau,
    const float* __restrict__ gam,
    float* __restrict__ h1s,
    unsigned long long* hp, unsigned long long* ep)
{
    const int chain = blockIdx.x & 15;
    const int slice = blockIdx.x >> 4;        // 0..7
    const int tid = threadIdx.x;
    const int w = tid >> 6;                   // wave in block 0..7
    const int lane = tid & 63;
    const int ks = lane & 7;                  // k-group within column
    const int colw = lane >> 3;               // column within wave 0..7
    const int j = slice * 64 + w * 8 + colw;  // output column 0..511
    const bool lead = (ks == 0);
    const int pk = 64 * w + lane;             // this lane's poll/stage index

    // 32 float4 = 128 regs of weights, asm-defined => register-resident
    float4 wC[16], wW[16];
    llc_load16(C1 + (size_t)j * HID + ks * 4, wC);
    llc_load16(W1 + (size_t)j * HID + ks * 4, wW);

    const float tauv = tau[0], gamv = gam[0];
    const float siga = fast_sigmoid(a1[j]);

    unsigned long long* hp_c = hp + (size_t)chain * HID;
    unsigned long long* ep_c = ep + (size_t)chain * HID;

    __shared__ float h_s[HID];
    __shared__ float e_s[HID];
    __shared__ float sq_s[8];

    float hj = 0.f;
    float cur_be0 = 0.f, cur_be1 = 0.f;
    if (lead) {
        cur_be0 = __builtin_nontemporal_load(&be0[(size_t)chain * HID + j]);
        cur_be1 = __builtin_nontemporal_load(&be1[(size_t)chain * HID + j]);
    }
    float cur_xs = __builtin_nontemporal_load(&xs1[chain]);

    // t=0: h(0) = 0, no poll needed
    h_s[tid] = 0.f;
    __syncthreads();

    for (int t = 0; t < T_LEN; ++t) {
        // prefetch next step's streams (overlaps polls)
        float nxt_be0 = 0.f, nxt_be1 = 0.f, nxt_xs = 0.f;
        if (t + 1 < T_LEN) {
            const size_t nrow = (size_t)((t + 1) * BATCH + chain) * HID;
            if (lead) {
                nxt_be0 = __builtin_nontemporal_load(&be0[nrow + j]);
                nxt_be1 = __builtin_nontemporal_load(&be1[nrow + j]);
            }
            nxt_xs = __builtin_nontemporal_load(&xs1[(t + 1) * BATCH + chain]);
        }
        const unsigned tag = (unsigned)(t + 1);

        // ---- phase 1: dp = (h @ C1^T)[j] from LDS, publish err pair ----
        {
            const float* hsb = h_s + ks * 4;
            float dp = 0.f;
            #pragma unroll
            for (int i = 0; i < 16; ++i) {
                float4 hv = *(const float4*)(hsb + 32 * i);  // broadcast, no conflicts
                dp += wC[i].x * hv.x + wC[i].y * hv.y
                    + wC[i].z * hv.z + wC[i].w * hv.w;
            }
            dp += __shfl_down(dp, 4, 8);
            dp += __shfl_down(dp, 2, 8);
            dp += __shfl_down(dp, 1, 8);
            if (lead) {
                float e = cur_be0 - fast_tanh(dp) * cur_xs;
                __hip_atomic_store(&ep_c[j], pack_pair(e, tag),
                                   __ATOMIC_RELAXED, __HIP_MEMORY_SCOPE_AGENT);
            }
        }

        // ---- poll err slice (coalesced: lane -> pair pk), stage to LDS ----
        {
            unsigned long long pv;
            for (;;) {
                pv = __hip_atomic_load(&ep_c[pk], __ATOMIC_RELAXED,
                                       __HIP_MEMORY_SCOPE_AGENT);
                if (__all(pair_epoch(pv) == tag)) break;
                __builtin_amdgcn_s_sleep(1);
            }
            float v = pair_val(pv);
            e_s[pk] = v;
            float sq = v * v;
            #pragma unroll
            for (int off = 32; off > 0; off >>= 1) sq += __shfl_down(sq, off, 64);
            if (lane == 0) sq_s[w] = sq;
        }
        __syncthreads();   // e_s + sq_s complete

        // ---- phase 2: ssq, ee = (err @ W1^T)[j] from LDS, gated update ----
        {
            float ssT = ((sq_s[0] + sq_s[1]) + (sq_s[2] + sq_s[3]))
                      + ((sq_s[4] + sq_s[5]) + (sq_s[6] + sq_s[7]));
            const float* esb = e_s + ks * 4;
            float ee = 0.f;
            #pragma unroll
            for (int i = 0; i < 16; ++i) {
                float4 ev = *(const float4*)(esb + 32 * i);
                ee += wW[i].x * ev.x + wW[i].y * ev.y
                    + wW[i].z * ev.z + wW[i].w * ev.w;
            }
            ee += __shfl_down(ee, 4, 8);
            ee += __shfl_down(ee, 2, 8);
            ee += __shfl_down(ee, 1, 8);
            if (lead) {
                float rel = fminf(sqrtf(ssT) / cur_xs, 4.0f);
                float s = fast_sigmoid((rel - tauv) / gamv);
                float input_h = hj * 0.2f + cur_be1 * 0.6f + ee * s * 0.2f;
                float g = s * siga;
                hj = hj * (1.f - g) + fast_tanh(input_h) * g;
                __hip_atomic_store(&hp_c[j], pack_pair(hj, tag),
                                   __ATOMIC_RELAXED, __HIP_MEMORY_SCOPE_AGENT);
                __builtin_nontemporal_store(hj,
                    &h1s[(size_t)(t * BATCH + chain) * HID + j]);
            }
        }

        // ---- poll h slice for next step (epoch t+1), stage to LDS ----
        if (t + 1 < T_LEN) {
            unsigned long long pv;
            for (;;) {
                pv = __hip_atomic_load(&hp_c[pk], __ATOMIC_RELAXED,
                                       __HIP_MEMORY_SCOPE_AGENT);
                if (__all(pair_epoch(pv) == tag)) break;
                __builtin_amdgcn_s_sleep(1);
            }
            h_s[pk] = pair_val(pv);
        }
        __syncthreads();   // h_s ready for next step

        cur_be0 = nxt_be0; cur_be1 = nxt_be1; cur_xs = nxt_xs;
    }
}

// K4: head matmul out[b,t,c] = [h1 || be1] @ head_w^T + head_b
__global__ __launch_bounds__(1024) void k4_head(const float* __restrict__ h1s,
                                                const float* __restrict__ be1,
                                                const float* __restrict__ head_w,
                                                const float* __restrict__ head_b,
                                                float* __restrict__ out) {
    const int t = blockIdx.x;
    const int tid = threadIdx.x;
    const int c = tid >> 4;
    const int b = tid & 15;
    const float* hw = head_w + c * (2 * HID);
    const float* x1 = h1s + (size_t)(t * BATCH + b) * HID;
    const float* x2 = be1 + (size_t)(t * BATCH + b) * HID;
    float acc0 = head_b[c], acc1 = 0.f;
    for (int k = 0; k < HID; k += 4) {
        float4 w = *(const float4*)(hw + k);
        float4 xv = *(const float4*)(x1 + k);
        acc0 += w.x * xv.x + w.y * xv.y + w.z * xv.z + w.w * xv.w;
    }
    for (int k = 0; k < HID; k += 4) {
        float4 w = *(const float4*)(hw + HID + k);
        float4 xv = *(const float4*)(x2 + k);
        acc1 += w.x * xv.x + w.y * xv.y + w.z * xv.z + w.w * xv.w;
    }
    out[b * (T_LEN * NCLS) + t * NCLS + c] = acc0 + acc1;
}

extern "C" void kernel_launch(void* const* d_in, const int* in_sizes, int n_in,
                              void* d_out, int out_size, void* d_ws, size_t ws_size,
                              hipStream_t stream) {
    const float* feats  = (const float*)d_in[0];
    const float* B0     = (const float*)d_in[2];
    const float* C1     = (const float*)d_in[7];
    const float* B1     = (const float*)d_in[8];
    const float* W1     = (const float*)d_in[9];
    const float* a1     = (const float*)d_in[10];
    const float* tau1   = (const float*)d_in[11];
    const float* gam1   = (const float*)d_in[12];
    const float* head_w = (const float*)d_in[13];
    const float* head_b = (const float*)d_in[14];
    float* out = (float*)d_out;

    float* be0 = (float*)d_ws;                          // T*B*HID
    float* be1 = be0 + (size_t)T_LEN * BATCH * HID;     // T*B*HID
    float* xs1 = be1 + (size_t)T_LEN * BATCH * HID;     // T*B
    float* h1s = xs1 + (size_t)T_LEN * BATCH;           // T*B*HID
    unsigned long long* hp =
        (unsigned long long*)(h1s + (size_t)T_LEN * BATCH * HID);  // B*HID u64
    unsigned long long* epr = hp + (size_t)BATCH * HID;            // B*HID u64

    hipLaunchKernelGGL(k0_init, dim3(32), dim3(256), 0, stream, hp, epr);
    hipLaunchKernelGGL(k1_be0, dim3(T_LEN), dim3(256), 0, stream, feats, B0, be0);
    hipLaunchKernelGGL(k2_be1, dim3(T_LEN), dim3(256), 0, stream, be0, B1, be1, xs1);
    hipLaunchKernelGGL(k3_fused, dim3(BATCH * SL), dim3(512), 0, stream,
                       be0, be1, xs1, C1, W1, a1, tau1, gam1, h1s, hp, epr);
    hipLaunchKernelGGL(k4_head, dim3(T_LEN), dim3(1024), 0, stream,
                       h1s, be1, head_w, head_b, out);
}